// Round 2
// baseline (896.934 us; speedup 1.0000x reference)
//
#include <hip/hip_runtime.h>
#include <math.h>

#define D 128
#define NB 8

__device__ __forceinline__ float wave_allsum(float v) {
    #pragma unroll
    for (int off = 32; off; off >>= 1) v += __shfl_xor(v, off);
    return v;
}

// h = relu(LN(x@W1+b1; g1,bt1));  A = h@We1[:128,:] + be1;  B = h@We1[128:,:]
__global__ void __launch_bounds__(128) transform_kernel(
    const float* __restrict__ x, const float* __restrict__ W1,
    const float* __restrict__ b1, const float* __restrict__ g1, const float* __restrict__ bt1,
    const float* __restrict__ We1, const float* __restrict__ be1,
    float* __restrict__ h, float* __restrict__ A, float* __restrict__ B, int N)
{
    __shared__ float xs[NB][D];
    __shared__ float hs[NB][D];
    __shared__ float redS[2][NB], redQ[2][NB];
    const int t = threadIdx.x;
    const int wid = t >> 6, lane = t & 63;
    const int base = blockIdx.x * NB;

    for (int n = 0; n < NB; ++n) {
        int node = base + n;
        xs[n][t] = (node < N) ? x[(size_t)node * D + t] : 0.f;
    }
    __syncthreads();

    float acc[NB];
    float bb = b1[t];
    #pragma unroll
    for (int n = 0; n < NB; ++n) acc[n] = bb;
    for (int k = 0; k < D; ++k) {
        float w = W1[k * D + t];
        #pragma unroll
        for (int n = 0; n < NB; ++n) acc[n] += xs[n][k] * w;
    }
    #pragma unroll
    for (int n = 0; n < NB; ++n) {
        float s = wave_allsum(acc[n]);
        float q = wave_allsum(acc[n] * acc[n]);
        if (lane == 0) { redS[wid][n] = s; redQ[wid][n] = q; }
    }
    __syncthreads();
    float gg = g1[t], bt = bt1[t];
    #pragma unroll
    for (int n = 0; n < NB; ++n) {
        float s = redS[0][n] + redS[1][n];
        float q = redQ[0][n] + redQ[1][n];
        float m = s * (1.f / D);
        float v = q * (1.f / D) - m * m;
        float hv = (acc[n] - m) * rsqrtf(v + 1e-5f) * gg + bt;
        hv = fmaxf(hv, 0.f);
        hs[n][t] = hv;
        int node = base + n;
        if (node < N) h[(size_t)node * D + t] = hv;
    }
    __syncthreads();

    float accA[NB], accB[NB];
    float ba = be1[t];
    #pragma unroll
    for (int n = 0; n < NB; ++n) { accA[n] = ba; accB[n] = 0.f; }
    for (int k = 0; k < D; ++k) {
        float wa = We1[k * D + t];
        float wb = We1[(k + D) * D + t];
        #pragma unroll
        for (int n = 0; n < NB; ++n) { accA[n] += hs[n][k] * wa; accB[n] += hs[n][k] * wb; }
    }
    #pragma unroll
    for (int n = 0; n < NB; ++n) {
        int node = base + n;
        if (node < N) {
            A[(size_t)node * D + t] = accA[n];
            B[(size_t)node * D + t] = accB[n];
        }
    }
}

// per edge: hidden = relu(A[row]+B[col]); w = sigmoid(hidden.We2 + be2);
// aggr[col] += w * h[row]   (one 64-lane wave per edge)
__global__ void __launch_bounds__(256) edge_kernel(
    const int* __restrict__ ei,
    const float* __restrict__ A, const float* __restrict__ B,
    const float* __restrict__ We2, const float* __restrict__ be2,
    const float* __restrict__ h, float* __restrict__ aggr, int E)
{
    const int wid = threadIdx.x >> 6, lane = threadIdx.x & 63;
    const int e = blockIdx.x * 4 + wid;
    if (e >= E) return;
    const int row = ei[e], col = ei[E + e];
    const float2* A2 = (const float2*)(A + (size_t)row * D);
    const float2* B2 = (const float2*)(B + (size_t)col * D);
    float2 a = A2[lane], b = B2[lane];
    float h0 = fmaxf(a.x + b.x, 0.f), h1 = fmaxf(a.y + b.y, 0.f);
    float2 ww = ((const float2*)We2)[lane];
    float part = h0 * ww.x + h1 * ww.y;
    part = wave_allsum(part);
    float ewt = 1.f / (1.f + expf(-(part + be2[0])));
    float2 hv = ((const float2*)(h + (size_t)row * D))[lane];
    float* dst = aggr + (size_t)col * D + 2 * lane;
    atomicAdd(dst, ewt * hv.x);
    atomicAdd(dst + 1, ewt * hv.y);
}

// gate = sigmoid(h@Wg[:128,:] + aggr@Wg[128:,:] + bg); h_new = gate*aggr+(1-gate)*h; out = LN(h_new; g2,bt2)
__global__ void __launch_bounds__(128) gate_kernel(
    const float* __restrict__ h, const float* __restrict__ aggr,
    const float* __restrict__ Wg, const float* __restrict__ bg,
    const float* __restrict__ g2, const float* __restrict__ bt2,
    float* __restrict__ out, int N)
{
    __shared__ float hs[NB][D], as_[NB][D];
    __shared__ float redS[2][NB], redQ[2][NB];
    const int t = threadIdx.x, wid = t >> 6, lane = t & 63;
    const int base = blockIdx.x * NB;
    for (int n = 0; n < NB; ++n) {
        int node = base + n;
        hs[n][t]  = (node < N) ? h[(size_t)node * D + t] : 0.f;
        as_[n][t] = (node < N) ? aggr[(size_t)node * D + t] : 0.f;
    }
    __syncthreads();
    float acc[NB];
    float bb = bg[t];
    #pragma unroll
    for (int n = 0; n < NB; ++n) acc[n] = bb;
    for (int k = 0; k < D; ++k) {
        float wt = Wg[k * D + t], wb = Wg[(k + D) * D + t];
        #pragma unroll
        for (int n = 0; n < NB; ++n) acc[n] += hs[n][k] * wt + as_[n][k] * wb;
    }
    float gg = g2[t], bt = bt2[t];
    float hn[NB];
    #pragma unroll
    for (int n = 0; n < NB; ++n) {
        float gate = 1.f / (1.f + expf(-acc[n]));
        hn[n] = gate * as_[n][t] + (1.f - gate) * hs[n][t];
        float s = wave_allsum(hn[n]);
        float q = wave_allsum(hn[n] * hn[n]);
        if (lane == 0) { redS[wid][n] = s; redQ[wid][n] = q; }
    }
    __syncthreads();
    #pragma unroll
    for (int n = 0; n < NB; ++n) {
        int node = base + n;
        if (node >= N) continue;
        float s = redS[0][n] + redS[1][n];
        float q = redQ[0][n] + redQ[1][n];
        float m = s * (1.f / D);
        float v = q * (1.f / D) - m * m;
        out[(size_t)node * D + t] = (hn[n] - m) * rsqrtf(v + 1e-5f) * gg + bt;
    }
}

extern "C" void kernel_launch(void* const* d_in, const int* in_sizes, int n_in,
                              void* d_out, int out_size, void* d_ws, size_t ws_size,
                              hipStream_t stream) {
    const float* x   = (const float*)d_in[0];
    const int*   ei  = (const int*)d_in[1];
    const float* W1  = (const float*)d_in[2];
    const float* b1  = (const float*)d_in[3];
    const float* g1  = (const float*)d_in[4];
    const float* bt1 = (const float*)d_in[5];
    const float* We1 = (const float*)d_in[6];
    const float* be1 = (const float*)d_in[7];
    const float* We2 = (const float*)d_in[8];
    const float* be2 = (const float*)d_in[9];
    // d_in[10..13]: Wn1,bn1,Wn2,bn2 — node_weights is dead code in the reference
    const float* Wg  = (const float*)d_in[14];
    const float* bg  = (const float*)d_in[15];
    const float* g2  = (const float*)d_in[16];
    const float* bt2 = (const float*)d_in[17];

    const int N = in_sizes[0] / D;
    const int E = in_sizes[1] / 2;

    float* h    = (float*)d_ws;
    float* A    = h + (size_t)N * D;
    float* B    = A + (size_t)N * D;
    float* aggr = B + (size_t)N * D;

    (void)hipMemsetAsync(aggr, 0, (size_t)N * D * sizeof(float), stream);

    const int nblk = (N + NB - 1) / NB;
    transform_kernel<<<nblk, 128, 0, stream>>>(x, W1, b1, g1, bt1, We1, be1, h, A, B, N);
    edge_kernel<<<(E + 3) / 4, 256, 0, stream>>>(ei, A, B, We2, be2, h, aggr, E);
    gate_kernel<<<nblk, 128, 0, stream>>>(h, aggr, Wg, bg, g2, bt2, (float*)d_out, N);
}

// Round 3
// 560.613 us; speedup vs baseline: 1.5999x; 1.5999x over previous
//
#include <hip/hip_runtime.h>
#include <math.h>

#define D 128
#define NB 8

__device__ __forceinline__ float wave_allsum(float v) {
    #pragma unroll
    for (int off = 32; off; off >>= 1) v += __shfl_xor(v, off);
    return v;
}

// h = relu(LN(x@W1+b1; g1,bt1));  A = h@We1[:128,:] + be1;  B = h@We1[128:,:]
__global__ void __launch_bounds__(128) transform_kernel(
    const float* __restrict__ x, const float* __restrict__ W1,
    const float* __restrict__ b1, const float* __restrict__ g1, const float* __restrict__ bt1,
    const float* __restrict__ We1, const float* __restrict__ be1,
    float* __restrict__ h, float* __restrict__ A, float* __restrict__ B, int N)
{
    __shared__ float xs[NB][D];
    __shared__ float hs[NB][D];
    __shared__ float redS[2][NB], redQ[2][NB];
    const int t = threadIdx.x;
    const int wid = t >> 6, lane = t & 63;
    const int base = blockIdx.x * NB;

    for (int n = 0; n < NB; ++n) {
        int node = base + n;
        xs[n][t] = (node < N) ? x[(size_t)node * D + t] : 0.f;
    }
    __syncthreads();

    float acc[NB];
    float bb = b1[t];
    #pragma unroll
    for (int n = 0; n < NB; ++n) acc[n] = bb;
    for (int k = 0; k < D; ++k) {
        float w = W1[k * D + t];
        #pragma unroll
        for (int n = 0; n < NB; ++n) acc[n] += xs[n][k] * w;
    }
    #pragma unroll
    for (int n = 0; n < NB; ++n) {
        float s = wave_allsum(acc[n]);
        float q = wave_allsum(acc[n] * acc[n]);
        if (lane == 0) { redS[wid][n] = s; redQ[wid][n] = q; }
    }
    __syncthreads();
    float gg = g1[t], bt = bt1[t];
    #pragma unroll
    for (int n = 0; n < NB; ++n) {
        float s = redS[0][n] + redS[1][n];
        float q = redQ[0][n] + redQ[1][n];
        float m = s * (1.f / D);
        float v = q * (1.f / D) - m * m;
        float hv = (acc[n] - m) * rsqrtf(v + 1e-5f) * gg + bt;
        hv = fmaxf(hv, 0.f);
        hs[n][t] = hv;
        int node = base + n;
        if (node < N) h[(size_t)node * D + t] = hv;
    }
    __syncthreads();

    float accA[NB], accB[NB];
    float ba = be1[t];
    #pragma unroll
    for (int n = 0; n < NB; ++n) { accA[n] = ba; accB[n] = 0.f; }
    for (int k = 0; k < D; ++k) {
        float wa = We1[k * D + t];
        float wb = We1[(k + D) * D + t];
        #pragma unroll
        for (int n = 0; n < NB; ++n) { accA[n] += hs[n][k] * wa; accB[n] += hs[n][k] * wb; }
    }
    #pragma unroll
    for (int n = 0; n < NB; ++n) {
        int node = base + n;
        if (node < N) {
            A[(size_t)node * D + t] = accA[n];
            B[(size_t)node * D + t] = accB[n];
        }
    }
}

// ---- CSR build: histogram of dst, exclusive scan, scatter src ids ----

__global__ void __launch_bounds__(256) hist_kernel(const int* __restrict__ ei,
                                                   int* __restrict__ deg, int E) {
    int e = blockIdx.x * 256 + threadIdx.x;
    if (e < E) atomicAdd(&deg[ei[E + e]], 1);
}

__global__ void __launch_bounds__(1024) scan_kernel(const int* __restrict__ deg,
                                                    int* __restrict__ off,
                                                    int* __restrict__ cursor, int N) {
    __shared__ int partial[1024];
    const int t = threadIdx.x;
    const int chunk = (N + 1023) / 1024;
    const int start = t * chunk;
    const int end = min(start + chunk, N);
    int s = 0;
    for (int i = start; i < end; ++i) s += deg[i];
    partial[t] = s;
    __syncthreads();
    for (int d = 1; d < 1024; d <<= 1) {
        int v = (t >= d) ? partial[t - d] : 0;
        __syncthreads();
        if (t >= d) partial[t] += v;
        __syncthreads();
    }
    int run = (t == 0) ? 0 : partial[t - 1];
    for (int i = start; i < end; ++i) {
        off[i] = run;
        cursor[i] = run;
        run += deg[i];
    }
    if (t == 0) off[N] = partial[1023];
}

__global__ void __launch_bounds__(256) scatter_kernel(const int* __restrict__ ei,
                                                      int* __restrict__ cursor,
                                                      int* __restrict__ ssrc, int E) {
    int e = blockIdx.x * 256 + threadIdx.x;
    if (e < E) {
        int pos = atomicAdd(&cursor[ei[E + e]], 1);
        ssrc[pos] = ei[e];
    }
}

// pull aggregation: one wave per dst node; no atomics.
// aggr[dst] = sum_{e: col[e]=dst} sigmoid(relu(A[src]+B[dst]).We2 + be2) * h[src]
__global__ void __launch_bounds__(256) agg_kernel(
    const int* __restrict__ off, const int* __restrict__ ssrc,
    const float* __restrict__ A, const float* __restrict__ B,
    const float* __restrict__ We2, const float* __restrict__ be2,
    const float* __restrict__ h, float* __restrict__ aggr, int N)
{
    const int wid = threadIdx.x >> 6, lane = threadIdx.x & 63;
    const int node = blockIdx.x * 4 + wid;
    if (node >= N) return;
    const float2 b = ((const float2*)(B + (size_t)node * D))[lane];
    const float2 ww = ((const float2*)We2)[lane];
    const float be = be2[0];
    float2 acc = make_float2(0.f, 0.f);
    const int s = off[node], e = off[node + 1];
    for (int j = s; j < e; ++j) {
        int src = ssrc[j];
        float2 a = ((const float2*)(A + (size_t)src * D))[lane];
        float2 hv = ((const float2*)(h + (size_t)src * D))[lane];
        float part = fmaxf(a.x + b.x, 0.f) * ww.x + fmaxf(a.y + b.y, 0.f) * ww.y;
        part = wave_allsum(part);
        float w = 1.f / (1.f + expf(-(part + be)));
        acc.x += w * hv.x;
        acc.y += w * hv.y;
    }
    ((float2*)(aggr + (size_t)node * D))[lane] = acc;
}

// gate = sigmoid(h@Wg[:128,:] + aggr@Wg[128:,:] + bg); h_new = gate*aggr+(1-gate)*h; out = LN(h_new; g2,bt2)
__global__ void __launch_bounds__(128) gate_kernel(
    const float* __restrict__ h, const float* __restrict__ aggr,
    const float* __restrict__ Wg, const float* __restrict__ bg,
    const float* __restrict__ g2, const float* __restrict__ bt2,
    float* __restrict__ out, int N)
{
    __shared__ float hs[NB][D], as_[NB][D];
    __shared__ float redS[2][NB], redQ[2][NB];
    const int t = threadIdx.x, wid = t >> 6, lane = t & 63;
    const int base = blockIdx.x * NB;
    for (int n = 0; n < NB; ++n) {
        int node = base + n;
        hs[n][t]  = (node < N) ? h[(size_t)node * D + t] : 0.f;
        as_[n][t] = (node < N) ? aggr[(size_t)node * D + t] : 0.f;
    }
    __syncthreads();
    float acc[NB];
    float bb = bg[t];
    #pragma unroll
    for (int n = 0; n < NB; ++n) acc[n] = bb;
    for (int k = 0; k < D; ++k) {
        float wt = Wg[k * D + t], wb = Wg[(k + D) * D + t];
        #pragma unroll
        for (int n = 0; n < NB; ++n) acc[n] += hs[n][k] * wt + as_[n][k] * wb;
    }
    float gg = g2[t], bt = bt2[t];
    float hn[NB];
    #pragma unroll
    for (int n = 0; n < NB; ++n) {
        float gate = 1.f / (1.f + expf(-acc[n]));
        hn[n] = gate * as_[n][t] + (1.f - gate) * hs[n][t];
        float s = wave_allsum(hn[n]);
        float q = wave_allsum(hn[n] * hn[n]);
        if (lane == 0) { redS[wid][n] = s; redQ[wid][n] = q; }
    }
    __syncthreads();
    #pragma unroll
    for (int n = 0; n < NB; ++n) {
        int node = base + n;
        if (node >= N) continue;
        float s = redS[0][n] + redS[1][n];
        float q = redQ[0][n] + redQ[1][n];
        float m = s * (1.f / D);
        float v = q * (1.f / D) - m * m;
        out[(size_t)node * D + t] = (hn[n] - m) * rsqrtf(v + 1e-5f) * gg + bt;
    }
}

extern "C" void kernel_launch(void* const* d_in, const int* in_sizes, int n_in,
                              void* d_out, int out_size, void* d_ws, size_t ws_size,
                              hipStream_t stream) {
    const float* x   = (const float*)d_in[0];
    const int*   ei  = (const int*)d_in[1];
    const float* W1  = (const float*)d_in[2];
    const float* b1  = (const float*)d_in[3];
    const float* g1  = (const float*)d_in[4];
    const float* bt1 = (const float*)d_in[5];
    const float* We1 = (const float*)d_in[6];
    const float* be1 = (const float*)d_in[7];
    const float* We2 = (const float*)d_in[8];
    const float* be2 = (const float*)d_in[9];
    // d_in[10..13]: Wn1,bn1,Wn2,bn2 — node_weights is dead code in the reference
    const float* Wg  = (const float*)d_in[14];
    const float* bg  = (const float*)d_in[15];
    const float* g2  = (const float*)d_in[16];
    const float* bt2 = (const float*)d_in[17];

    const int N = in_sizes[0] / D;
    const int E = in_sizes[1] / 2;

    float* h    = (float*)d_ws;
    float* A    = h + (size_t)N * D;
    float* B    = A + (size_t)N * D;
    float* aggr = B + (size_t)N * D;
    int* deg    = (int*)(aggr + (size_t)N * D);
    int* off    = deg + (N + 1);
    int* cursor = off + (N + 1);
    int* ssrc   = cursor + (N + 1);

    (void)hipMemsetAsync(deg, 0, (size_t)(N + 1) * sizeof(int), stream);

    const int nblk = (N + NB - 1) / NB;
    transform_kernel<<<nblk, 128, 0, stream>>>(x, W1, b1, g1, bt1, We1, be1, h, A, B, N);
    hist_kernel<<<(E + 255) / 256, 256, 0, stream>>>(ei, deg, E);
    scan_kernel<<<1, 1024, 0, stream>>>(deg, off, cursor, N);
    scatter_kernel<<<(E + 255) / 256, 256, 0, stream>>>(ei, cursor, ssrc, E);
    agg_kernel<<<(N + 3) / 4, 256, 0, stream>>>(off, ssrc, A, B, We2, be2, h, aggr, N);
    gate_kernel<<<nblk, 128, 0, stream>>>(h, aggr, Wg, bg, g2, bt2, (float*)d_out, N);
}